// Round 11
// baseline (508.273 us; speedup 1.0000x reference)
//
#include <hip/hip_runtime.h>
#include <hip/hip_bf16.h>
#include <hip/hip_fp16.h>
#include <math.h>

#define N_NODES 50000
#define N_EDGES 800000
#define ET      (N_EDGES + N_NODES)   // with self loops
#define IN_DIM  128
#define HEADS   4
#define HID     64
#define HC      256                   // HEADS*HID
#define OUTD    128

typedef _Float16 half8 __attribute__((ext_vector_type(8)));
typedef float f32x4 __attribute__((ext_vector_type(4)));

// ---------------- CSR build ----------------

// one-block full exclusive scan of counts -> offs (N_NODES elements)
__global__ __launch_bounds__(1024) void scan_all_k(const int* __restrict__ counts,
                                                   int* __restrict__ offs) {
    __shared__ int sm[1024];
    constexpr int T = 1024;
    constexpr int CH = (N_NODES + T - 1) / T;    // 49
    const int t = threadIdx.x;
    const int base = t * CH;
    int s = 0;
    for (int i = 0; i < CH; ++i) {
        int idx = base + i;
        if (idx < N_NODES) s += counts[idx];
    }
    sm[t] = s;
    __syncthreads();
    for (int o = 1; o < T; o <<= 1) {
        int add = (t >= o) ? sm[t - o] : 0;
        __syncthreads();
        sm[t] += add;
        __syncthreads();
    }
    int run = sm[t] - s;                         // exclusive prefix for this thread
    for (int i = 0; i < CH; ++i) {
        int idx = base + i;
        if (idx < N_NODES) { offs[idx] = run; run += counts[idx]; }
    }
    if (t == 0) offs[N_NODES] = ET;
}

// fill using counts as a countdown cursor (counts holds degree post-hist)
__global__ void fill_k(const int* __restrict__ ei, const int* __restrict__ offs,
                       int* __restrict__ counts, int* __restrict__ csr) {
    int i = blockIdx.x * blockDim.x + threadIdx.x;
    if (i >= ET) return;
    int sv, dv;
    if (i < N_EDGES) { sv = ei[i]; dv = ei[N_EDGES + i]; }
    else             { sv = dv = i - N_EDGES; }
    int pos = offs[dv] + atomicSub(&counts[dv], 1) - 1;
    csr[pos] = sv;
}

// ---------------- fused setup: hist + x->fp16 + W transposes + zero S2/D2 ----

#define J_HIST  ET                       // 850000
#define J_CVT   (N_NODES * IN_DIM / 4)   // 1600000
#define J_W     131072
#define SETUP_TOTAL (J_HIST + J_CVT + J_W + 2 * N_NODES)

__global__ void setup_k(const int* __restrict__ ei, int* __restrict__ counts,
                        const float* __restrict__ x, __half* __restrict__ xh,
                        const float* __restrict__ W0, __half* __restrict__ Wt0,
                        const float* __restrict__ W1, __half* __restrict__ Wt1,
                        const float* __restrict__ W2, __half* __restrict__ Wt2,
                        float* __restrict__ S2, float* __restrict__ D2) {
    int g = blockIdx.x * 256 + threadIdx.x;
    if (g < J_HIST) {
        int dv = (g < N_EDGES) ? ei[N_EDGES + g] : (g - N_EDGES);
        atomicAdd(&counts[dv], 1);
        return;
    }
    g -= J_HIST;
    if (g < J_CVT) {
        float4 v = *(const float4*)(x + (size_t)g * 4);
        union { __half2 h2[2]; float2 f2; } u;
        u.h2[0] = __floats2half2_rn(v.x, v.y);
        u.h2[1] = __floats2half2_rn(v.z, v.w);
        *(float2*)(xh + (size_t)g * 4) = u.f2;
        return;
    }
    g -= J_CVT;
    if (g < J_W) {
        if (g < 32768) {
            int n = g / IN_DIM, k = g - n * IN_DIM;
            Wt0[g] = __float2half(W0[(size_t)k * HC + n]);
        } else if (g < 98304) {
            int i = g - 32768;
            int n = i / HC, k = i - n * HC;
            Wt1[i] = __float2half(W1[(size_t)k * HC + n]);
        } else {
            int i = g - 98304;
            int n = i / HC, k = i - n * HC;
            Wt2[i] = __float2half(W2[(size_t)k * OUTD + n]);
        }
        return;
    }
    g -= J_W;
    if (g < N_NODES) { S2[g] = 0.f; return; }
    g -= N_NODES;
    if (g < N_NODES) D2[g] = 0.f;
}

// ------- MFMA fp16 GEMM + fused attention scores (transposed accumulator) ----
// r8 structure with BK=128: LDS 64KB (A,B each 128x128 halfs), K=256 -> only
// 2 barrier pairs, K=128 -> 1. mfma(b,a) -> lane holds 4 consecutive C-cols.
// Non-ATOMIC (CD=64): wave wn in col-block y owns head 2y+wn -> direct store.
// ATOMIC (CD=128, H=1): head split across waves -> atomicAdd (pre-zeroed).

__device__ __forceinline__ void async_copy16(void* lds_base, const void* gaddr) {
    __builtin_amdgcn_global_load_lds(
        (const __attribute__((address_space(1))) unsigned int*)gaddr,
        (__attribute__((address_space(3))) unsigned int*)lds_base,
        16, 0, 0);
}

#define CPAD 132   // padded row length (halfs) for the LDS C repack tile

template<int H, int CD, bool ATOMIC>
__global__ __launch_bounds__(256) void gemm_mfma_k(const __half* __restrict__ A,
                                                   const __half* __restrict__ Wt,
                                                   __half* __restrict__ C,
                                                   const float* __restrict__ asrc,
                                                   const float* __restrict__ adst,
                                                   float* __restrict__ S,
                                                   float* __restrict__ D,
                                                   int M, int K, int N) {
    __shared__ __attribute__((aligned(16))) __half smem[2 * 128 * 128]; // 64 KB
    __half* Ah = smem;                    // 128 rows x 128 halfs
    __half* Bh = smem + 128 * 128;
    const int t = threadIdx.x;
    const int w = t >> 6;
    const int lane = t & 63;
    const int wm = w >> 1, wn = w & 1;
    const int cc = lane & 15;             // C-row within 16-block
    const int quad = lane >> 4;           // C-col quad / k-quad
    const int row0 = blockIdx.x * 128;
    const int col0 = blockIdx.y * 128;

    f32x4 acc[4][4];
    #pragma unroll
    for (int i = 0; i < 4; ++i)
        #pragma unroll
        for (int j = 0; j < 4; ++j) acc[i][j] = (f32x4){0.f, 0.f, 0.f, 0.f};

    // staging: one async_copy16 covers 4 rows x 128 halfs (1KB)
    const int srow = lane >> 4;           // 0..3
    const int skq  = (lane & 15) * 8;     // 0..120

    for (int k0 = 0; k0 < K; k0 += 128) {
        __syncthreads();
        #pragma unroll
        for (int hh = 0; hh < 8; ++hh) {
            int ra = row0 + w * 32 + hh * 4 + srow;
            if (ra > M - 1) ra = M - 1;                    // clamp (results discarded)
            async_copy16(&Ah[(w * 32 + hh * 4) * 128],
                         A + (size_t)ra * K + k0 + skq);
            int rb = col0 + w * 32 + hh * 4 + srow;        // N mult of 128
            async_copy16(&Bh[(w * 32 + hh * 4) * 128],
                         Wt + (size_t)rb * K + k0 + skq);
        }
        __syncthreads();
        #pragma unroll
        for (int c = 0; c < 4; ++c) {
            half8 a[4], b[4];
            #pragma unroll
            for (int i = 0; i < 4; ++i)
                a[i] = *(const half8*)&Ah[(wm * 64 + i * 16 + cc) * 128 + c * 32 + quad * 8];
            #pragma unroll
            for (int j = 0; j < 4; ++j)
                b[j] = *(const half8*)&Bh[(wn * 64 + j * 16 + cc) * 128 + c * 32 + quad * 8];
            #pragma unroll
            for (int i = 0; i < 4; ++i)
                #pragma unroll
                for (int j = 0; j < 4; ++j)
                    acc[i][j] = __builtin_amdgcn_mfma_f32_16x16x32_f16(b[j], a[i], acc[i][j], 0, 0, 0);
        }
    }

    // ---- fused scores (registers + shfl only) ----
    const int hh_ = ATOMIC ? 0 : (blockIdx.y * 2 + wn);
    float4 asj[4], adj[4];
    #pragma unroll
    for (int j = 0; j < 4; ++j) {
        int cb = (ATOMIC ? wn * 64 : 0) + j * 16 + quad * 4;
        asj[j] = *(const float4*)&asrc[hh_ * CD + cb];
        adj[j] = *(const float4*)&adst[hh_ * CD + cb];
    }
    #pragma unroll
    for (int i = 0; i < 4; ++i) {
        float sv = 0.f, dv = 0.f;
        #pragma unroll
        for (int j = 0; j < 4; ++j) {
            sv = fmaf(acc[i][j][0], asj[j].x, sv); dv = fmaf(acc[i][j][0], adj[j].x, dv);
            sv = fmaf(acc[i][j][1], asj[j].y, sv); dv = fmaf(acc[i][j][1], adj[j].y, dv);
            sv = fmaf(acc[i][j][2], asj[j].z, sv); dv = fmaf(acc[i][j][2], adj[j].z, dv);
            sv = fmaf(acc[i][j][3], asj[j].w, sv); dv = fmaf(acc[i][j][3], adj[j].w, dv);
        }
        sv += __shfl_xor(sv, 16, 64); dv += __shfl_xor(dv, 16, 64);
        sv += __shfl_xor(sv, 32, 64); dv += __shfl_xor(dv, 32, 64);
        int r = row0 + wm * 64 + i * 16 + cc;
        if (quad == 0 && r < M) {
            if constexpr (ATOMIC) {
                atomicAdd(&S[r], sv);
                atomicAdd(&D[r], dv);
            } else {
                S[(size_t)r * H + hh_] = sv;
                D[(size_t)r * H + hh_] = dv;
            }
        }
    }

    // ---- C store via LDS repack (reuse smem as padded 128 x CPAD tile) ----
    __syncthreads();
    #pragma unroll
    for (int i = 0; i < 4; ++i) {
        int tr = wm * 64 + i * 16 + cc;
        #pragma unroll
        for (int j = 0; j < 4; ++j) {
            int tc = wn * 64 + j * 16 + quad * 4;
            union { __half2 h2[2]; uint2 u2; } pk;
            pk.h2[0] = __floats2half2_rn(acc[i][j][0], acc[i][j][1]);
            pk.h2[1] = __floats2half2_rn(acc[i][j][2], acc[i][j][3]);
            *(uint2*)&smem[tr * CPAD + tc] = pk.u2;
        }
    }
    __syncthreads();
    #pragma unroll
    for (int rr = 0; rr < 8; ++rr) {
        int r = rr * 16 + (t >> 4);
        int ccol = (t & 15) * 8;
        int gr = row0 + r;
        if (gr < M) {
            uint4 v = *(const uint4*)&smem[r * CPAD + ccol];
            *(uint4*)&C[(size_t)gr * N + col0 + ccol] = v;
        }
    }
}

// ---------------- per-dst-node aggregation (r8 version: U=8, row-major) -------
// Direct exp (no running max): |e| << 80 for these weight scales; z > 0.

template<int H, int C, bool ELU_OUT, typename OT>
__global__ __launch_bounds__(256) void aggr_k(const __half* __restrict__ xp,
                                              const float* __restrict__ s,
                                              const float* __restrict__ d,
                                              const int* __restrict__ offs,
                                              const int* __restrict__ csr,
                                              const float* __restrict__ bias,
                                              OT* __restrict__ out) {
    constexpr int HCl = H * C;
    constexpr int EPL = HCl / 64;
    constexpr int U = 8;
    int wid = blockIdx.x * 4 + (threadIdx.x >> 6);
    int lane = threadIdx.x & 63;
    if (wid >= N_NODES) return;
    int h = (lane * EPL) / C;
    float dh = d[(size_t)wid * H + h];
    float z = 0.f;
    float acc[EPL];
    #pragma unroll
    for (int k = 0; k < EPL; ++k) acc[k] = 0.f;

    auto loadrow = [&](int src, float* v) {
        const __half* xr = xp + (size_t)src * HCl + lane * EPL;
        if constexpr (EPL == 4) {
            union { float2 f2; __half2 h2[2]; } u;
            u.f2 = *(const float2*)xr;
            float2 a = __half22float2(u.h2[0]);
            float2 b = __half22float2(u.h2[1]);
            v[0] = a.x; v[1] = a.y; v[2] = b.x; v[3] = b.y;
        } else {
            union { float f; __half2 h2; } u;
            u.f = *(const float*)xr;
            float2 a = __half22float2(u.h2);
            v[0] = a.x; v[1] = a.y;
        }
    };

    int e0 = offs[wid], e1 = offs[wid + 1];
    int j = e0;
    for (; j + U <= e1; j += U) {
        int srcs[U];
        #pragma unroll
        for (int u = 0; u < U; ++u) srcs[u] = csr[j + u];
        float ev[U];
        #pragma unroll
        for (int u = 0; u < U; ++u) ev[u] = s[(size_t)srcs[u] * H + h];
        float v[U][EPL];
        #pragma unroll
        for (int u = 0; u < U; ++u) loadrow(srcs[u], v[u]);
        #pragma unroll
        for (int u = 0; u < U; ++u) {
            float e = ev[u] + dh;
            e = (e > 0.f) ? e : 0.2f * e;          // leaky_relu
            float p = __expf(e);
            z += p;
            #pragma unroll
            for (int k = 0; k < EPL; ++k) acc[k] += p * v[u][k];
        }
    }
    for (; j < e1; ++j) {
        int sv = csr[j];
        float e = s[(size_t)sv * H + h] + dh;
        e = (e > 0.f) ? e : 0.2f * e;
        float p = __expf(e);
        float v[EPL];
        loadrow(sv, v);
        z += p;
        #pragma unroll
        for (int k = 0; k < EPL; ++k) acc[k] += p * v[k];
    }

    float inv = 1.f / (z + 1e-16f);
    float o[EPL];
    #pragma unroll
    for (int k = 0; k < EPL; ++k) {
        o[k] = acc[k] * inv + bias[lane * EPL + k];
        if constexpr (ELU_OUT) o[k] = (o[k] > 0.f) ? o[k] : (__expf(o[k]) - 1.f);
    }
    if constexpr (sizeof(OT) == 2 && EPL == 4) {
        union { __half2 h2[2]; float2 f2; } u;
        u.h2[0] = __floats2half2_rn(o[0], o[1]);
        u.h2[1] = __floats2half2_rn(o[2], o[3]);
        *(float2*)((__half*)out + (size_t)wid * HCl + lane * EPL) = u.f2;
    } else {
        #pragma unroll
        for (int k = 0; k < EPL; ++k)
            out[(size_t)wid * HCl + lane * EPL + k] = (OT)o[k];
    }
}

// ---------------- launch ----------------

extern "C" void kernel_launch(void* const* d_in, const int* in_sizes, int n_in,
                              void* d_out, int out_size, void* d_ws, size_t ws_size,
                              hipStream_t stream) {
    const float* x      = (const float*)d_in[0];
    const int*   ei     = (const int*)  d_in[1];
    const float* W0     = (const float*)d_in[2];
    const float* as0    = (const float*)d_in[3];
    const float* ad0    = (const float*)d_in[4];
    const float* b0     = (const float*)d_in[5];
    const float* W1     = (const float*)d_in[6];
    const float* as1    = (const float*)d_in[7];
    const float* ad1    = (const float*)d_in[8];
    const float* b1     = (const float*)d_in[9];
    const float* W2     = (const float*)d_in[10];
    const float* as2    = (const float*)d_in[11];
    const float* ad2    = (const float*)d_in[12];
    const float* b2     = (const float*)d_in[13];
    float* out = (float*)d_out;

    // workspace layout (256B aligned chunks)
    char* p = (char*)d_ws;
    auto take = [&](size_t bytes) {
        char* r = p;
        p += (bytes + 255) & ~(size_t)255;
        return r;
    };
    __half* XPh   = (__half*)take((size_t)N_NODES * HC * 2);
    __half* Hbuf  = (__half*)take((size_t)N_NODES * HC * 2);
    __half* xh    = (__half*)take((size_t)N_NODES * IN_DIM * 2);
    __half* Wt0   = (__half*)take((size_t)IN_DIM * HC * 2);
    __half* Wt1   = (__half*)take((size_t)HC * HC * 2);
    __half* Wt2   = (__half*)take((size_t)HC * OUTD * 2);
    float*  S     = (float*) take((size_t)N_NODES * HEADS * 4);
    float*  D     = (float*) take((size_t)N_NODES * HEADS * 4);
    float*  S2    = (float*) take((size_t)N_NODES * 4);
    float*  D2    = (float*) take((size_t)N_NODES * 4);
    int*    counts= (int*)   take((size_t)N_NODES * 4);
    int*    offs  = (int*)   take((size_t)(N_NODES + 1) * 4);
    int*    csr   = (int*)   take((size_t)ET * 4);

    const int ET_BLOCKS = (ET + 255) / 256;
    const int NODE_BLOCKS = (N_NODES + 3) / 4;   // 12500
    const int MB = (N_NODES + 127) / 128;        // 391
    dim3 g0(MB, HC / 128);                       // 391 x 2
    dim3 g2(MB, OUTD / 128);                     // 391 x 1

    // ---- setup ----
    hipMemsetAsync(counts, 0, (size_t)N_NODES * 4, stream);
    setup_k<<<(SETUP_TOTAL + 255) / 256, 256, 0, stream>>>(
        ei, counts, x, xh, W0, Wt0, W1, Wt1, W2, Wt2, S2, D2);

    // ---- CSR scan + fill ----
    scan_all_k<<<1, 1024, 0, stream>>>(counts, offs);
    fill_k<<<ET_BLOCKS, 256, 0, stream>>>(ei, offs, counts, csr);

    // ---- layer 0: 128 -> 4x64, concat, ELU ----
    gemm_mfma_k<HEADS, HID, false><<<g0, 256, 0, stream>>>(xh, Wt0, XPh, as0, ad0, S, D, N_NODES, IN_DIM, HC);
    aggr_k<HEADS, HID, true, __half><<<NODE_BLOCKS, 256, 0, stream>>>(XPh, S, D, offs, csr, b0, Hbuf);

    // ---- layer 1: 256 -> 4x64, concat, ELU ----
    gemm_mfma_k<HEADS, HID, false><<<g0, 256, 0, stream>>>(Hbuf, Wt1, XPh, as1, ad1, S, D, N_NODES, HC, HC);
    aggr_k<HEADS, HID, true, __half><<<NODE_BLOCKS, 256, 0, stream>>>(XPh, S, D, offs, csr, b1, Hbuf);

    // ---- layer 2: 256 -> 1x128, mean(H=1), no ELU ----
    gemm_mfma_k<1, OUTD, true><<<g2, 256, 0, stream>>>(Hbuf, Wt2, XPh, as2, ad2, S2, D2, N_NODES, HC, OUTD);
    aggr_k<1, OUTD, false, float><<<NODE_BLOCKS, 256, 0, stream>>>(XPh, S2, D2, offs, csr, b2, out);
}

// Round 12
// 412.454 us; speedup vs baseline: 1.2323x; 1.2323x over previous
//
#include <hip/hip_runtime.h>
#include <hip/hip_bf16.h>
#include <hip/hip_fp16.h>
#include <math.h>

#define N_NODES 50000
#define N_EDGES 800000
#define ET      (N_EDGES + N_NODES)   // with self loops
#define IN_DIM  128
#define HEADS   4
#define HID     64
#define HC      256                   // HEADS*HID
#define OUTD    128

typedef _Float16 half8 __attribute__((ext_vector_type(8)));
typedef float f32x4 __attribute__((ext_vector_type(4)));

// ---------------- CSR build ----------------

__global__ void scan1_k(const int* __restrict__ counts, int* __restrict__ offs,
                        int* __restrict__ bsums) {
    __shared__ int sm[512];
    int tid = threadIdx.x;
    int i = blockIdx.x * 512 + tid;
    int v = (i < N_NODES) ? counts[i] : 0;
    sm[tid] = v;
    __syncthreads();
    #pragma unroll
    for (int o = 1; o < 512; o <<= 1) {
        int add = (tid >= o) ? sm[tid - o] : 0;
        __syncthreads();
        sm[tid] += add;
        __syncthreads();
    }
    if (i < N_NODES) offs[i] = sm[tid] - v;        // exclusive within block
    if (tid == 511) bsums[blockIdx.x] = sm[511];
}

// adds prefix of bsums; each block computes its own prefix redundantly
// (98 entries: <=2 loads/lane + 6 shuffles in wave 0) -- replaces scan2+scan3
__global__ void scan3_k(int* __restrict__ offs, const int* __restrict__ bsums) {
    __shared__ int base_sm;
    int tid = threadIdx.x;
    if (tid < 64) {
        int p = 0;
        for (int j = tid; j < (int)blockIdx.x; j += 64) p += bsums[j];
        #pragma unroll
        for (int o = 1; o < 64; o <<= 1) p += __shfl_xor(p, o, 64);
        if (tid == 0) base_sm = p;
    }
    __syncthreads();
    int i = blockIdx.x * 512 + tid;
    if (i < N_NODES) offs[i] += base_sm;
    if (i == 0) offs[N_NODES] = ET;
}

// fill using counts as a countdown cursor (counts holds degree post-hist)
__global__ void fill_k(const int* __restrict__ ei, const int* __restrict__ offs,
                       int* __restrict__ counts, int* __restrict__ csr) {
    int i = blockIdx.x * blockDim.x + threadIdx.x;
    if (i >= ET) return;
    int sv, dv;
    if (i < N_EDGES) { sv = ei[i]; dv = ei[N_EDGES + i]; }
    else             { sv = dv = i - N_EDGES; }
    int pos = offs[dv] + atomicSub(&counts[dv], 1) - 1;
    csr[pos] = sv;
}

// ---------------- fused setup: hist + x->fp16 + W transposes + zero S2/D2 ----

#define J_HIST  ET                       // 850000
#define J_CVT   (N_NODES * IN_DIM / 4)   // 1600000
#define J_W     131072
#define SETUP_TOTAL (J_HIST + J_CVT + J_W + 2 * N_NODES)

__global__ void setup_k(const int* __restrict__ ei, int* __restrict__ counts,
                        const float* __restrict__ x, __half* __restrict__ xh,
                        const float* __restrict__ W0, __half* __restrict__ Wt0,
                        const float* __restrict__ W1, __half* __restrict__ Wt1,
                        const float* __restrict__ W2, __half* __restrict__ Wt2,
                        float* __restrict__ S2, float* __restrict__ D2) {
    int g = blockIdx.x * 256 + threadIdx.x;
    if (g < J_HIST) {
        int dv = (g < N_EDGES) ? ei[N_EDGES + g] : (g - N_EDGES);
        atomicAdd(&counts[dv], 1);
        return;
    }
    g -= J_HIST;
    if (g < J_CVT) {
        float4 v = *(const float4*)(x + (size_t)g * 4);
        union { __half2 h2[2]; float2 f2; } u;
        u.h2[0] = __floats2half2_rn(v.x, v.y);
        u.h2[1] = __floats2half2_rn(v.z, v.w);
        *(float2*)(xh + (size_t)g * 4) = u.f2;
        return;
    }
    g -= J_CVT;
    if (g < J_W) {
        if (g < 32768) {
            int n = g / IN_DIM, k = g - n * IN_DIM;
            Wt0[g] = __float2half(W0[(size_t)k * HC + n]);
        } else if (g < 98304) {
            int i = g - 32768;
            int n = i / HC, k = i - n * HC;
            Wt1[i] = __float2half(W1[(size_t)k * HC + n]);
        } else {
            int i = g - 98304;
            int n = i / HC, k = i - n * HC;
            Wt2[i] = __float2half(W2[(size_t)k * OUTD + n]);
        }
        return;
    }
    g -= J_W;
    if (g < N_NODES) { S2[g] = 0.f; return; }
    g -= N_NODES;
    if (g < N_NODES) D2[g] = 0.f;
}

// ------- MFMA fp16 GEMM + fused attention scores (transposed accumulator) ----
// C[M][N] = A[M][K] * Wt[N][K]^T.  mfma(b, a, acc) computes C^T fragments:
// lane holds C[row = i*16 + (lane&15)][cols = j*16 + (lane>>4)*4 + reg] -->
// 4 consecutive cols per lane per (i,j): vectorizable stores + cheap row-sums.
// s[r][h] = sum_c C[r][h*CD+c]*asrc[h][c] (same for d/adst) from fp32 acc.
// 128x128 block tile, 4 waves (64x64 each), 16x16x32 f16 MFMA, BK=64.
// Non-ATOMIC (CD=64): wave's 64 cols = one full head -> direct store.
// ATOMIC (CD=128, H=1): head split across 2 waves -> atomicAdd (pre-zeroed).

__device__ __forceinline__ void async_copy16(void* lds_base, const void* gaddr) {
    __builtin_amdgcn_global_load_lds(
        (const __attribute__((address_space(1))) unsigned int*)gaddr,
        (__attribute__((address_space(3))) unsigned int*)lds_base,
        16, 0, 0);
}

#define CPAD 132   // padded row length (halfs) for the LDS C tile

template<int H, int CD, bool ATOMIC>
__global__ __launch_bounds__(256) void gemm_mfma_k(const __half* __restrict__ A,
                                                   const __half* __restrict__ Wt,
                                                   __half* __restrict__ C,
                                                   const float* __restrict__ asrc,
                                                   const float* __restrict__ adst,
                                                   float* __restrict__ S,
                                                   float* __restrict__ D,
                                                   int M, int K, int N) {
    __shared__ __attribute__((aligned(16))) __half smem[128 * CPAD]; // >= 2*128*64
    __half* Ah = smem;
    __half* Bh = smem + 128 * 64;
    const int t = threadIdx.x;
    const int w = t >> 6;
    const int lane = t & 63;
    const int wm = w >> 1, wn = w & 1;
    const int cc = lane & 15;        // C-row within 16-block
    const int quad = lane >> 4;      // C-col quad
    const int row0 = blockIdx.x * 128;
    const int col0 = blockIdx.y * 128;

    f32x4 acc[4][4];
    #pragma unroll
    for (int i = 0; i < 4; ++i)
        #pragma unroll
        for (int j = 0; j < 4; ++j) acc[i][j] = (f32x4){0.f, 0.f, 0.f, 0.f};

    const int srow = lane >> 3;
    const int skq  = (lane & 7) * 8;

    for (int k0 = 0; k0 < K; k0 += 64) {
        __syncthreads();
        #pragma unroll
        for (int hh = 0; hh < 4; ++hh) {
            int ra = row0 + w * 32 + hh * 8 + srow;
            if (ra > M - 1) ra = M - 1;                    // clamp (results discarded)
            async_copy16(&Ah[(w * 32 + hh * 8) * 64],
                         A + (size_t)ra * K + k0 + skq);
            int rb = col0 + w * 32 + hh * 8 + srow;        // N multiple of 128
            async_copy16(&Bh[(w * 32 + hh * 8) * 64],
                         Wt + (size_t)rb * K + k0 + skq);
        }
        __syncthreads();
        #pragma unroll
        for (int c = 0; c < 2; ++c) {
            half8 a[4], b[4];
            #pragma unroll
            for (int i = 0; i < 4; ++i)
                a[i] = *(const half8*)&Ah[(wm * 64 + i * 16 + cc) * 64 + c * 32 + quad * 8];
            #pragma unroll
            for (int j = 0; j < 4; ++j)
                b[j] = *(const half8*)&Bh[(wn * 64 + j * 16 + cc) * 64 + c * 32 + quad * 8];
            #pragma unroll
            for (int i = 0; i < 4; ++i)
                #pragma unroll
                for (int j = 0; j < 4; ++j)
                    acc[i][j] = __builtin_amdgcn_mfma_f32_16x16x32_f16(b[j], a[i], acc[i][j], 0, 0, 0);
        }
    }

    // ---- fused scores (registers + shfl only) ----
    const int hh_ = ATOMIC ? 0 : (blockIdx.y * 2 + wn);
    float4 asj[4], adj[4];
    #pragma unroll
    for (int j = 0; j < 4; ++j) {
        int cb = (ATOMIC ? wn * 64 : 0) + j * 16 + quad * 4;
        asj[j] = *(const float4*)&asrc[hh_ * CD + cb];
        adj[j] = *(const float4*)&adst[hh_ * CD + cb];
    }
    #pragma unroll
    for (int i = 0; i < 4; ++i) {
        float sv = 0.f, dv = 0.f;
        #pragma unroll
        for (int j = 0; j < 4; ++j) {
            sv = fmaf(acc[i][j][0], asj[j].x, sv); dv = fmaf(acc[i][j][0], adj[j].x, dv);
            sv = fmaf(acc[i][j][1], asj[j].y, sv); dv = fmaf(acc[i][j][1], adj[j].y, dv);
            sv = fmaf(acc[i][j][2], asj[j].z, sv); dv = fmaf(acc[i][j][2], adj[j].z, dv);
            sv = fmaf(acc[i][j][3], asj[j].w, sv); dv = fmaf(acc[i][j][3], adj[j].w, dv);
        }
        sv += __shfl_xor(sv, 16, 64); dv += __shfl_xor(dv, 16, 64);
        sv += __shfl_xor(sv, 32, 64); dv += __shfl_xor(dv, 32, 64);
        int r = row0 + wm * 64 + i * 16 + cc;
        if (quad == 0 && r < M) {
            if constexpr (ATOMIC) {
                atomicAdd(&S[r], sv);
                atomicAdd(&D[r], dv);
            } else {
                S[(size_t)r * H + hh_] = sv;
                D[(size_t)r * H + hh_] = dv;
            }
        }
    }

    // ---- C store via LDS repack (reuse smem as padded 128 x CPAD tile) ----
    __syncthreads();   // everyone done reading Ah/Bh
    #pragma unroll
    for (int i = 0; i < 4; ++i) {
        int tr = wm * 64 + i * 16 + cc;
        #pragma unroll
        for (int j = 0; j < 4; ++j) {
            int tc = wn * 64 + j * 16 + quad * 4;
            union { __half2 h2[2]; uint2 u2; } pk;
            pk.h2[0] = __floats2half2_rn(acc[i][j][0], acc[i][j][1]);
            pk.h2[1] = __floats2half2_rn(acc[i][j][2], acc[i][j][3]);
            *(uint2*)&smem[tr * CPAD + tc] = pk.u2;
        }
    }
    __syncthreads();
    #pragma unroll
    for (int rr = 0; rr < 8; ++rr) {
        int r = rr * 16 + (t >> 4);
        int ccol = (t & 15) * 8;
        uint4 v = *(const uint4*)&smem[r * CPAD + ccol];
        int gr = row0 + r;
        if (gr < M)
            *(uint4*)&C[(size_t)gr * N + col0 + ccol] = v;
    }
}

// ---------------- per-dst-node aggregation (direct exp, no running max) --------
// Safe: |e| = |leaky_relu(s+d)| << 80 for these weight scales, so exp can't
// overflow; z >= self-loop term > 0. alpha identical to max-shifted softmax.

template<int H, int C, bool ELU_OUT, typename OT>
__global__ __launch_bounds__(256) void aggr_k(const __half* __restrict__ xp,
                                              const float* __restrict__ s,
                                              const float* __restrict__ d,
                                              const int* __restrict__ offs,
                                              const int* __restrict__ csr,
                                              const float* __restrict__ bias,
                                              OT* __restrict__ out) {
    constexpr int HCl = H * C;
    constexpr int EPL = HCl / 64;
    constexpr int U = 8;
    int wid = blockIdx.x * 4 + (threadIdx.x >> 6);
    int lane = threadIdx.x & 63;
    if (wid >= N_NODES) return;
    int h = (lane * EPL) / C;
    float dh = d[(size_t)wid * H + h];
    float z = 0.f;
    float acc[EPL];
    #pragma unroll
    for (int k = 0; k < EPL; ++k) acc[k] = 0.f;

    auto loadrow = [&](int src, float* v) {
        const __half* xr = xp + (size_t)src * HCl + lane * EPL;
        if constexpr (EPL == 4) {
            union { float2 f2; __half2 h2[2]; } u;
            u.f2 = *(const float2*)xr;
            float2 a = __half22float2(u.h2[0]);
            float2 b = __half22float2(u.h2[1]);
            v[0] = a.x; v[1] = a.y; v[2] = b.x; v[3] = b.y;
        } else {
            union { float f; __half2 h2; } u;
            u.f = *(const float*)xr;
            float2 a = __half22float2(u.h2);
            v[0] = a.x; v[1] = a.y;
        }
    };

    int e0 = offs[wid], e1 = offs[wid + 1];
    int j = e0;
    for (; j + U <= e1; j += U) {
        int srcs[U];
        #pragma unroll
        for (int u = 0; u < U; ++u) srcs[u] = csr[j + u];
        float ev[U];
        #pragma unroll
        for (int u = 0; u < U; ++u) ev[u] = s[(size_t)srcs[u] * H + h];
        float v[U][EPL];
        #pragma unroll
        for (int u = 0; u < U; ++u) loadrow(srcs[u], v[u]);
        #pragma unroll
        for (int u = 0; u < U; ++u) {
            float e = ev[u] + dh;
            e = (e > 0.f) ? e : 0.2f * e;          // leaky_relu
            float p = __expf(e);
            z += p;
            #pragma unroll
            for (int k = 0; k < EPL; ++k) acc[k] += p * v[u][k];
        }
    }
    for (; j < e1; ++j) {
        int sv = csr[j];
        float e = s[(size_t)sv * H + h] + dh;
        e = (e > 0.f) ? e : 0.2f * e;
        float p = __expf(e);
        float v[EPL];
        loadrow(sv, v);
        z += p;
        #pragma unroll
        for (int k = 0; k < EPL; ++k) acc[k] += p * v[k];
    }

    float inv = 1.f / (z + 1e-16f);
    float o[EPL];
    #pragma unroll
    for (int k = 0; k < EPL; ++k) {
        o[k] = acc[k] * inv + bias[lane * EPL + k];
        if constexpr (ELU_OUT) o[k] = (o[k] > 0.f) ? o[k] : (__expf(o[k]) - 1.f);
    }
    if constexpr (sizeof(OT) == 2 && EPL == 4) {
        union { __half2 h2[2]; float2 f2; } u;
        u.h2[0] = __floats2half2_rn(o[0], o[1]);
        u.h2[1] = __floats2half2_rn(o[2], o[3]);
        *(float2*)((__half*)out + (size_t)wid * HCl + lane * EPL) = u.f2;
    } else {
        #pragma unroll
        for (int k = 0; k < EPL; ++k)
            out[(size_t)wid * HCl + lane * EPL + k] = (OT)o[k];
    }
}

// ---------------- launch ----------------

extern "C" void kernel_launch(void* const* d_in, const int* in_sizes, int n_in,
                              void* d_out, int out_size, void* d_ws, size_t ws_size,
                              hipStream_t stream) {
    const float* x      = (const float*)d_in[0];
    const int*   ei     = (const int*)  d_in[1];
    const float* W0     = (const float*)d_in[2];
    const float* as0    = (const float*)d_in[3];
    const float* ad0    = (const float*)d_in[4];
    const float* b0     = (const float*)d_in[5];
    const float* W1     = (const float*)d_in[6];
    const float* as1    = (const float*)d_in[7];
    const float* ad1    = (const float*)d_in[8];
    const float* b1     = (const float*)d_in[9];
    const float* W2     = (const float*)d_in[10];
    const float* as2    = (const float*)d_in[11];
    const float* ad2    = (const float*)d_in[12];
    const float* b2     = (const float*)d_in[13];
    float* out = (float*)d_out;

    // workspace layout (256B aligned chunks)
    char* p = (char*)d_ws;
    auto take = [&](size_t bytes) {
        char* r = p;
        p += (bytes + 255) & ~(size_t)255;
        return r;
    };
    __half* XPh   = (__half*)take((size_t)N_NODES * HC * 2);
    __half* Hbuf  = (__half*)take((size_t)N_NODES * HC * 2);
    __half* xh    = (__half*)take((size_t)N_NODES * IN_DIM * 2);
    __half* Wt0   = (__half*)take((size_t)IN_DIM * HC * 2);
    __half* Wt1   = (__half*)take((size_t)HC * HC * 2);
    __half* Wt2   = (__half*)take((size_t)HC * OUTD * 2);
    float*  S     = (float*) take((size_t)N_NODES * HEADS * 4);
    float*  D     = (float*) take((size_t)N_NODES * HEADS * 4);
    float*  S2    = (float*) take((size_t)N_NODES * 4);
    float*  D2    = (float*) take((size_t)N_NODES * 4);
    int*    counts= (int*)   take((size_t)N_NODES * 4);
    int*    offs  = (int*)   take((size_t)(N_NODES + 1) * 4);
    int*    bsums = (int*)   take(512 * 4);
    int*    csr   = (int*)   take((size_t)ET * 4);

    const int NB_SCAN = (N_NODES + 511) / 512;   // 98
    const int ET_BLOCKS = (ET + 255) / 256;
    const int NODE_BLOCKS = (N_NODES + 3) / 4;   // 12500
    const int MB = (N_NODES + 127) / 128;        // 391
    dim3 g0(MB, HC / 128);                       // 391 x 2
    dim3 g2(MB, OUTD / 128);                     // 391 x 1

    // ---- setup: zero counts; fused hist + cvt + wtrans + zero S2/D2 ----
    hipMemsetAsync(counts, 0, (size_t)N_NODES * 4, stream);
    setup_k<<<(SETUP_TOTAL + 255) / 256, 256, 0, stream>>>(
        ei, counts, x, xh, W0, Wt0, W1, Wt1, W2, Wt2, S2, D2);

    // ---- CSR scan + fill ----
    scan1_k<<<NB_SCAN, 512, 0, stream>>>(counts, offs, bsums);
    scan3_k<<<NB_SCAN, 512, 0, stream>>>(offs, bsums);
    fill_k<<<ET_BLOCKS, 256, 0, stream>>>(ei, offs, counts, csr);

    // ---- layer 0: 128 -> 4x64, concat, ELU ----
    gemm_mfma_k<HEADS, HID, false><<<g0, 256, 0, stream>>>(xh, Wt0, XPh, as0, ad0, S, D, N_NODES, IN_DIM, HC);
    aggr_k<HEADS, HID, true, __half><<<NODE_BLOCKS, 256, 0, stream>>>(XPh, S, D, offs, csr, b0, Hbuf);

    // ---- layer 1: 256 -> 4x64, concat, ELU ----
    gemm_mfma_k<HEADS, HID, false><<<g0, 256, 0, stream>>>(Hbuf, Wt1, XPh, as1, ad1, S, D, N_NODES, HC, HC);
    aggr_k<HEADS, HID, true, __half><<<NODE_BLOCKS, 256, 0, stream>>>(XPh, S, D, offs, csr, b1, Hbuf);

    // ---- layer 2: 256 -> 1x128, mean(H=1), no ELU ----
    gemm_mfma_k<1, OUTD, true><<<g2, 256, 0, stream>>>(Hbuf, Wt2, XPh, as2, ad2, S2, D2, N_NODES, HC, OUTD);
    aggr_k<1, OUTD, false, float><<<NODE_BLOCKS, 256, 0, stream>>>(XPh, S2, D2, offs, csr, b2, out);
}